// Round 11
// baseline (742.323 us; speedup 1.0000x reference)
//
#include <hip/hip_runtime.h>
#include <hip/hip_cooperative_groups.h>
#include <hip/hip_bf16.h>
#include <hip/hip_fp16.h>

namespace cg = cooperative_groups;

#define B_  4
#define V_  256
#define H_  512
#define E_  32640   // V*(V-1)/2

typedef _Float16 half8 __attribute__((ext_vector_type(8)));
typedef float    f32x4 __attribute__((ext_vector_type(4)));
typedef unsigned int uint4v __attribute__((ext_vector_type(4)));

// Fast erf (Abramowitz-Stegun 7.1.26, |err| <= 1.5e-7), branchless.
__device__ __forceinline__ float gelu_f(float x) {
    float u = x * 0.70710678118654752f;
    float a = fabsf(u);
    float t = __builtin_amdgcn_rcpf(fmaf(0.3275911f, a, 1.0f));
    float poly = t * fmaf(t, fmaf(t, fmaf(t, fmaf(t, 1.061405429f, -1.453152027f),
                                          1.421413741f), -0.284496736f), 0.254829592f);
    float ex = __expf(-u * u);
    float erfa = fmaf(-poly, ex, 1.0f);
    float erfu = copysignf(erfa, u);
    return 0.5f * x * (1.0f + erfu);
}

__device__ __forceinline__ float wred_add(float v) {
    #pragma unroll
    for (int off = 32; off > 0; off >>= 1) v += __shfl_xor(v, off, 64);
    return v;
}

__device__ __forceinline__ void split16(float v, _Float16* hi, _Float16* lo) {
    _Float16 h = (_Float16)v;
    *hi = h; *lo = (_Float16)(v - (float)h);
}

__device__ __forceinline__ unsigned packf(float v) {
    _Float16 h = (_Float16)v;
    _Float16 l = (_Float16)(v - (float)h);
    unsigned hu = (unsigned)__builtin_bit_cast(unsigned short, h);
    unsigned lu = (unsigned)__builtin_bit_cast(unsigned short, l);
    return hu | (lu << 16);
}

__device__ __forceinline__ void unpk8(const unsigned* p, half8& hi, half8& lo) {
    uint4v a = *(const uint4v*)p;
    uint4v b = *(const uint4v*)(p + 4);
    uint4v hw, lw;
    hw[0] = (a[0] & 0xFFFFu) | (a[1] << 16);  lw[0] = (a[0] >> 16) | (a[1] & 0xFFFF0000u);
    hw[1] = (a[2] & 0xFFFFu) | (a[3] << 16);  lw[1] = (a[2] >> 16) | (a[3] & 0xFFFF0000u);
    hw[2] = (b[0] & 0xFFFFu) | (b[1] << 16);  lw[2] = (b[0] >> 16) | (b[1] & 0xFFFF0000u);
    hw[3] = (b[2] & 0xFFFFu) | (b[3] << 16);  lw[3] = (b[2] >> 16) | (b[3] & 0xFFFF0000u);
    hi = __builtin_bit_cast(half8, hw);
    lo = __builtin_bit_cast(half8, lw);
}

__device__ __forceinline__ size_t fmoff(int R, int row, int k) {
    return ((size_t)(k >> 3) * R + row) * 8 + (k & 7);
}

// ---------------------------------------------------------------- params
struct FrontParams {
    const float *verts, *wp, *bp;
    float *x; _Float16 *xfh, *xfl;
    const float *w2; _Float16 *w2f; int2 *etab;
    const float *in_w; _Float16 *iwfh, *iwfl;
    const float *out_w; _Float16 *owfh, *owfl;
    const float *w1; _Float16 *w1fh, *w1fl;
    const float *in_b, *out_b, *b1;
    unsigned *QKp, *Vp, *ctxp;
    float *Amat, *Bmat; _Float16 *Ahf, *Bhf;
    float *P; float2 *statsA, *statsB;
};

// ---------------------------------------------------------------- stage bodies (device fns)
__device__ __forceinline__ void setup_item(int t, const FrontParams& p) {
    if (t < 524288) {
        int row = t >> 9, k = t & 511;
        const float* vr = p.verts + row * 3;
        const float* wr = p.wp + k * 3;
        float val = vr[0] * wr[0] + vr[1] * wr[1] + vr[2] * wr[2] + p.bp[k];
        p.x[t] = val;
        size_t fo = fmoff(1024, row, k);
        split16(val, p.xfh + fo, p.xfl + fo);
        return;
    }
    t -= 524288;
    if (t < 131072) {
        int col = t >> 9, k = t & 511;
        p.w2f[fmoff(256, col, k)] = (_Float16)p.w2[(size_t)col * 512 + k];
        return;
    }
    t -= 131072;
    if (t < 32640) {
        double disc = (double)(2 * V_ - 1) * (2 * V_ - 1) - 8.0 * (double)t;
        int i = (int)((2 * V_ - 1 - sqrt(disc)) * 0.5);
        if (i < 0) i = 0;
        if (i > V_ - 2) i = V_ - 2;
        while (i < V_ - 2 && (i + 1) * (2 * V_ - 1 - (i + 1)) / 2 <= t) ++i;
        while (i > 0 && i * (2 * V_ - 1 - i) / 2 > t) --i;
        int j = t - i * (2 * V_ - 1 - i) / 2 + i + 1;
        p.etab[t] = make_int2(i, j);
        return;
    }
    t -= 32640;
    if (t < 786432) {
        int col = t >> 9, k = t & 511;
        size_t fo = fmoff(1536, col, k);
        split16(p.in_w[t], p.iwfh + fo, p.iwfl + fo);
        return;
    }
    t -= 786432;
    if (t < 262144) {
        int col = t >> 9, k = t & 511;
        size_t fo = fmoff(512, col, k);
        split16(p.out_w[t], p.owfh + fo, p.owfl + fo);
        return;
    }
    t -= 262144;
    {
        int col = t >> 9, k = t & 511;
        float v = (col < 512) ? p.w1[col * 1024 + k] : p.w1[(col - 512) * 1024 + 512 + k];
        size_t fo = fmoff(1024, col, k);
        split16(v, p.w1fh + fo, p.w1fl + fo);
    }
}

// 32x64-tile split-fp16 GEMM
// MODE 1: A packed (unpk8); C=x(+bias+res); split16 -> Fh/Fl planes.
// MODE 2: col<512 -> C(+bias)+Fh ; col>=512 -> C2+F2h.
// MODE 3: packed epilogue -> QKp via Fh, Vp via C2.
template<int MODE>
__device__ __forceinline__ void gemm_tile(
        int tile, int tilesN, int N,
        const _Float16* Ahf, const _Float16* Alf,
        const _Float16* Whf, const _Float16* Wlf,
        const float* bias, const float* res,
        float* C, _Float16* Fh, _Float16* Fl, float* C2, _Float16* F2h,
        int w, int l)
{
    const int lr = l & 15, lg = l >> 4;
    const int mg = w >> 1, ng = w & 1;
    const int row0 = (tile / tilesN) * 32 + mg * 16;
    const int col0 = (tile % tilesN) * 64 + ng * 32;

    f32x4 acc[2] = {};
    for (int kk = 0; kk < 16; ++kk) {
        const int kg = kk * 4 + lg;
        half8 ah, al, bh[2], bl[2];
        size_t aoff = ((size_t)kg * 1024 + row0 + lr) * 8;
        if (MODE == 1) {
            unpk8((const unsigned*)Ahf + aoff, ah, al);
        } else {
            ah = *(const half8*)(Ahf + aoff);
            al = *(const half8*)(Alf + aoff);
        }
        #pragma unroll
        for (int ni = 0; ni < 2; ++ni) {
            size_t boff = ((size_t)kg * N + col0 + ni * 16 + lr) * 8;
            bh[ni] = *(const half8*)(Whf + boff);
            bl[ni] = *(const half8*)(Wlf + boff);
        }
        #pragma unroll
        for (int ni = 0; ni < 2; ++ni) {
            acc[ni] = __builtin_amdgcn_mfma_f32_16x16x32_f16(ah, bh[ni], acc[ni], 0, 0, 0);
            acc[ni] = __builtin_amdgcn_mfma_f32_16x16x32_f16(ah, bl[ni], acc[ni], 0, 0, 0);
            acc[ni] = __builtin_amdgcn_mfma_f32_16x16x32_f16(al, bh[ni], acc[ni], 0, 0, 0);
        }
    }
    #pragma unroll
    for (int ni = 0; ni < 2; ++ni)
        #pragma unroll
        for (int r = 0; r < 4; ++r) {
            int row = row0 + lg * 4 + r;
            int col = col0 + ni * 16 + lr;
            float v = acc[ni][r];
            if (MODE == 1) {
                size_t idx = (size_t)row * 512 + col;
                v += bias[col] + res[idx];
                C[idx] = v;
                size_t fo = fmoff(1024, row, col);
                split16(v, Fh + fo, Fl + fo);
            } else if (MODE == 2) {
                if (col < 512) {
                    size_t idx = (size_t)row * 512 + col;
                    v += bias[col];
                    C[idx] = v;
                    Fh[fmoff(1024, row, col)] = (_Float16)v;
                } else {
                    int c2 = col - 512;
                    C2[(size_t)row * 512 + c2] = v;
                    F2h[fmoff(1024, row, c2)] = (_Float16)v;
                }
            } else {  // MODE 3
                v += bias[col];
                int bb = row >> 8, tok = row & 255;
                if (col < 1024) {
                    int hp = col >> 6, d = col & 63;
                    size_t off = (((size_t)(bb * 16 + hp) * 8 + (d >> 3)) * 256 + tok) * 8 + (d & 7);
                    ((unsigned*)Fh)[off] = packf(v);
                } else {
                    int c = col - 1024, hp = c >> 6, d = c & 63;
                    size_t off = (((size_t)(bb * 8 + hp) * 32 + (tok >> 3)) * 64 + d) * 8 + (tok & 7);
                    ((unsigned*)C2)[off] = packf(v);
                }
            }
        }
}

// attention job (one b,h,q-block; wave-private pbuf slice)
__device__ __forceinline__ void attn_job(int job, int w, int l,
                                         unsigned (&pb)[16][132],
                                         const FrontParams& p) {
    const int lr = l & 15, lg = l >> 4;
    const int bh = job >> 2;
    const int b = bh >> 3, h = bh & 7;
    const int qb = job & 3;
    const int q0 = qb * 64 + w * 16;
    const size_t qbase = (size_t)(b * 16 + h) * 8;
    const size_t kbase = (size_t)(b * 16 + 8 + h) * 8;
    const size_t vbase = (size_t)(b * 8 + h) * 32;

    half8 qh[2], ql[2];
    #pragma unroll
    for (int ks = 0; ks < 2; ++ks) {
        size_t off = ((qbase + ks * 4 + lg) * 256 + q0 + lr) * 8;
        unpk8(p.QKp + off, qh[ks], ql[ks]);
    }
    // pass 1: row max over all 256 keys
    float mr[4] = {-1e30f, -1e30f, -1e30f, -1e30f};
    #pragma unroll
    for (int kt = 0; kt < 16; ++kt) {
        f32x4 a = {};
        #pragma unroll
        for (int ks = 0; ks < 2; ++ks) {
            size_t off = ((kbase + ks * 4 + lg) * 256 + kt * 16 + lr) * 8;
            half8 kh, kl;
            unpk8(p.QKp + off, kh, kl);
            a = __builtin_amdgcn_mfma_f32_16x16x32_f16(qh[ks], kh, a, 0, 0, 0);
            a = __builtin_amdgcn_mfma_f32_16x16x32_f16(qh[ks], kl, a, 0, 0, 0);
            a = __builtin_amdgcn_mfma_f32_16x16x32_f16(ql[ks], kh, a, 0, 0, 0);
        }
        #pragma unroll
        for (int r = 0; r < 4; ++r) mr[r] = fmaxf(mr[r], a[r]);
    }
    #pragma unroll
    for (int off = 1; off < 16; off <<= 1)
        #pragma unroll
        for (int r = 0; r < 4; ++r) mr[r] = fmaxf(mr[r], __shfl_xor(mr[r], off, 64));

    // pass 2: two key-halves -> exp -> packed P in LDS -> PV
    float Ls[4] = {};
    f32x4 o[4] = {};
    #pragma unroll
    for (int H = 0; H < 2; ++H) {
        #pragma unroll
        for (int kt2 = 0; kt2 < 8; ++kt2) {
            const int kt = H * 8 + kt2;
            f32x4 a = {};
            #pragma unroll
            for (int ks = 0; ks < 2; ++ks) {
                size_t off = ((kbase + ks * 4 + lg) * 256 + kt * 16 + lr) * 8;
                half8 kh, kl;
                unpk8(p.QKp + off, kh, kl);
                a = __builtin_amdgcn_mfma_f32_16x16x32_f16(qh[ks], kh, a, 0, 0, 0);
                a = __builtin_amdgcn_mfma_f32_16x16x32_f16(qh[ks], kl, a, 0, 0, 0);
                a = __builtin_amdgcn_mfma_f32_16x16x32_f16(ql[ks], kh, a, 0, 0, 0);
            }
            #pragma unroll
            for (int r = 0; r < 4; ++r) {
                float pv = __expf((a[r] - mr[r]) * 0.125f);
                Ls[r] += pv;
                pb[lg * 4 + r][kt2 * 16 + lr] = packf(pv);
            }
        }
        #pragma unroll
        for (int ks = 0; ks < 4; ++ks) {
            half8 pah, pal;
            unpk8(&pb[lr][ks * 32 + lg * 8], pah, pal);
            #pragma unroll
            for (int nt = 0; nt < 4; ++nt) {
                size_t off = ((vbase + (size_t)(H * 4 + ks) * 4 + lg) * 64 + nt * 16 + lr) * 8;
                half8 vbh, vbl;
                unpk8(p.Vp + off, vbh, vbl);
                o[nt] = __builtin_amdgcn_mfma_f32_16x16x32_f16(pah, vbh, o[nt], 0, 0, 0);
                o[nt] = __builtin_amdgcn_mfma_f32_16x16x32_f16(pah, vbl, o[nt], 0, 0, 0);
                o[nt] = __builtin_amdgcn_mfma_f32_16x16x32_f16(pal, vbh, o[nt], 0, 0, 0);
            }
        }
    }
    #pragma unroll
    for (int off = 1; off < 16; off <<= 1)
        #pragma unroll
        for (int r = 0; r < 4; ++r) Ls[r] += __shfl_xor(Ls[r], off, 64);
    float Linv[4];
    #pragma unroll
    for (int r = 0; r < 4; ++r) Linv[r] = 1.0f / Ls[r];
    #pragma unroll
    for (int nt = 0; nt < 4; ++nt)
        #pragma unroll
        for (int r = 0; r < 4; ++r) {
            float val = o[nt][r] * Linv[r];
            int row = b * 256 + q0 + lg * 4 + r;
            int col = h * 64 + nt * 16 + lr;
            p.ctxp[fmoff(1024, row, col)] = packf(val);
        }
}

// pair dots + row stats job
__device__ __forceinline__ void pair_job(int job, int tid, const FrontParams& p) {
    const int w = tid >> 6, l = tid & 63;
    const int lr = l & 15, lg = l >> 4;
    if (job < 256) {
        const int t = job * 4 + w;
        const int b = t >> 8, tt = t & 255;
        const int i0 = (tt >> 4) * 16, j0 = (tt & 15) * 16;
        f32x4 acc = {};
        for (int kk = 0; kk < 16; ++kk) {
            const int kg = kk * 4 + lg;
            half8 af = *(const half8*)(p.Ahf + ((size_t)kg * 1024 + b * 256 + i0 + lr) * 8);
            half8 bf = *(const half8*)(p.Bhf + ((size_t)kg * 1024 + b * 256 + j0 + lr) * 8);
            acc = __builtin_amdgcn_mfma_f32_16x16x32_f16(af, bf, acc, 0, 0, 0);
        }
        #pragma unroll
        for (int r = 0; r < 4; ++r)
            p.P[((size_t)b << 16) + (size_t)(i0 + lg * 4 + r) * 256 + j0 + lr] = acc[r];
    } else {
        const int sid = job - 256;
        const int slice = tid >> 4, lane = tid & 15;
        const int m = sid * 16 + slice;
        const float* src = (m < 1024 ? p.Amat + (size_t)m * 512 : p.Bmat + (size_t)(m - 1024) * 512);
        float s = 0.0f, sq = 0.0f;
        #pragma unroll
        for (int i = 0; i < 8; ++i) {
            f32x4 v = *(const f32x4*)(src + i * 64 + lane * 4);
            s  += v[0] + v[1] + v[2] + v[3];
            sq += v[0]*v[0] + v[1]*v[1] + v[2]*v[2] + v[3]*v[3];
        }
        #pragma unroll
        for (int off = 8; off > 0; off >>= 1) {
            s  += __shfl_xor(s, off, 64);
            sq += __shfl_xor(sq, off, 64);
        }
        if (lane == 0) {
            if (m < 1024) p.statsA[m] = make_float2(s, sq);
            else          p.statsB[m - 1024] = make_float2(s, sq);
        }
    }
}

// ---------------------------------------------------------------- cooperative front-end
__global__ __launch_bounds__(256, 4) void k_front(FrontParams p) {
    __shared__ unsigned pbuf[4][16][132];
    cg::grid_group grid = cg::this_grid();
    const int tid = threadIdx.x;
    const int w = tid >> 6, l = tid & 63;
    const int nb = gridDim.x;

    for (int t0 = blockIdx.x * 256 + tid; t0 < 2260864; t0 += nb * 256)
        setup_item(t0, p);
    grid.sync();

    for (int tile = blockIdx.x; tile < 768; tile += nb)
        gemm_tile<3>(tile, 24, 1536, p.xfh, p.xfl, p.iwfh, p.iwfl, p.in_b, nullptr,
                     nullptr, (_Float16*)p.QKp, nullptr, (float*)p.Vp, nullptr, w, l);
    grid.sync();

    for (int job = blockIdx.x; job < 128; job += nb)
        attn_job(job, w, l, pbuf[w], p);
    grid.sync();

    for (int tile = blockIdx.x; tile < 256; tile += nb)
        gemm_tile<1>(tile, 8, 512, (const _Float16*)p.ctxp, nullptr, p.owfh, p.owfl,
                     p.out_b, p.x, p.x, p.xfh, p.xfl, nullptr, nullptr, w, l);
    grid.sync();

    for (int tile = blockIdx.x; tile < 512; tile += nb)
        gemm_tile<2>(tile, 16, 1024, p.xfh, p.xfl, p.w1fh, p.w1fl, p.b1, nullptr,
                     p.Amat, p.Ahf, nullptr, p.Bmat, p.Bhf, w, l);
    grid.sync();

    for (int job = blockIdx.x; job < 384; job += nb)
        pair_job(job, tid, p);
}

// ---------------------------------------------------------------- fallback stage kernels
__global__ __launch_bounds__(256) void k_s0(FrontParams p) {
    int t = blockIdx.x * 256 + threadIdx.x;
    if (t < 2260864) setup_item(t, p);
}
__global__ __launch_bounds__(256) void k_s2(FrontParams p) {
    const int tid = threadIdx.x;
    gemm_tile<3>(blockIdx.x, 24, 1536, p.xfh, p.xfl, p.iwfh, p.iwfl, p.in_b, nullptr,
                 nullptr, (_Float16*)p.QKp, nullptr, (float*)p.Vp, nullptr, tid >> 6, tid & 63);
}
__global__ __launch_bounds__(256) void k_s4(FrontParams p) {
    __shared__ unsigned pbuf[4][16][132];
    const int tid = threadIdx.x;
    attn_job(blockIdx.x, tid >> 6, tid & 63, pbuf[tid >> 6], p);
}
__global__ __launch_bounds__(256) void k_s6(FrontParams p) {
    const int tid = threadIdx.x;
    gemm_tile<1>(blockIdx.x, 8, 512, (const _Float16*)p.ctxp, nullptr, p.owfh, p.owfl,
                 p.out_b, p.x, p.x, p.xfh, p.xfl, nullptr, nullptr, tid >> 6, tid & 63);
}
__global__ __launch_bounds__(256) void k_s8(FrontParams p) {
    const int tid = threadIdx.x;
    gemm_tile<2>(blockIdx.x, 16, 1024, p.xfh, p.xfl, p.w1fh, p.w1fl, p.b1, nullptr,
                 p.Amat, p.Ahf, nullptr, p.Bmat, p.Bhf, tid >> 6, tid & 63);
}
__global__ __launch_bounds__(256) void k_s10(FrontParams p) {
    pair_job(blockIdx.x, threadIdx.x, p);
}

// ---------------------------------------------------------------- fused edge MLP (unchanged R8)
__global__ __launch_bounds__(512, 8) void k_edge(
        const float* __restrict__ Am, const float* __restrict__ Bm,
        const _Float16* __restrict__ w2f,
        const float* __restrict__ g1, const float* __restrict__ be1,
        const float* __restrict__ b2, const float* __restrict__ g2,
        const float* __restrict__ be2, const float* __restrict__ w3,
        const float* __restrict__ b3, const int2* __restrict__ etab,
        const float2* __restrict__ statsA, const float2* __restrict__ statsB,
        const float* __restrict__ P, float* __restrict__ out)
{
    extern __shared__ unsigned char smem[];   // 32768 B
    const int tid = threadIdx.x;
    const int w = tid >> 6;
    const int l = tid & 63;
    const int bid0 = blockIdx.x;
    const int swz = (bid0 & 7) * 510 + (bid0 >> 3);
    const int b  = swz / 1020;
    const int eb = swz % 1020;

    {
        const int e  = w * 4 + (l >> 4);
        const int kq = l & 15;
        int2 ij = etab[eb * 32 + e];
        float2 sa = statsA[b * 256 + ij.x];
        float2 sb = statsB[b * 256 + ij.y];
        float pij = P[((size_t)b << 16) + ((size_t)ij.x << 8) + ij.y];
        float mean = (sa.x + sb.x) * (1.0f / 512.0f);
        float ex2  = (sa.y + sb.y + 2.0f * pij) * (1.0f / 512.0f);
        float rstd = rsqrtf(ex2 - mean * mean + 1e-5f);
        const float* ar = Am + (((size_t)(b * 256 + ij.x)) << 9);
        const float* br = Bm + (((size_t)(b * 256 + ij.y)) << 9);
        #pragma unroll
        for (int t = 0; t < 4; ++t) {
            const int kg = kq + 16 * t;
            const int k0 = kg * 8;
            f32x4 a0 = *(const f32x4*)(ar + k0);
            f32x4 a1 = *(const f32x4*)(ar + k0 + 4);
            f32x4 c0 = *(const f32x4*)(br + k0);
            f32x4 c1 = *(const f32x4*)(br + k0 + 4);
            f32x4 ga = *(const f32x4*)(g1 + k0);
            f32x4 gb = *(const f32x4*)(g1 + k0 + 4);
            f32x4 ea = *(const f32x4*)(be1 + k0);
            f32x4 ebv= *(const f32x4*)(be1 + k0 + 4);
            half8 hv;
            #pragma unroll
            for (int c = 0; c < 4; ++c) {
                float xa = ((a0[c] + c0[c]) - mean) * rstd * ga[c] + ea[c];
                float xb = ((a1[c] + c1[c]) - mean) * rstd * gb[c] + ebv[c];
                hv[c]     = (_Float16)gelu_f(xa);
                hv[c + 4] = (_Float16)gelu_f(xb);
            }
            *(half8*)(smem + kg * 512 + ((e ^ (kg & 7)) << 4)) = hv;
        }
    }
    __syncthreads();

    f32x4 acc[2][2] = {};
    const int lg = l >> 4, lr = l & 15;
    const int col0 = w * 32;
    #pragma unroll
    for (int kk = 0; kk < 16; ++kk) {
        const int kg = kk * 4 + lg;
        half8 bf[2];
        #pragma unroll
        for (int ni = 0; ni < 2; ++ni)
            bf[ni] = *(const half8*)(w2f + ((size_t)kg * 256 + col0 + ni * 16 + lr) * 8);
        half8 af[2];
        #pragma unroll
        for (int mi = 0; mi < 2; ++mi)
            af[mi] = *(const half8*)(smem + kg * 512 + (((mi * 16 + lr) ^ (kg & 7)) << 4));
        #pragma unroll
        for (int mi = 0; mi < 2; ++mi)
            #pragma unroll
            for (int ni = 0; ni < 2; ++ni)
                acc[mi][ni] = __builtin_amdgcn_mfma_f32_16x16x32_f16(af[mi], bf[ni], acc[mi][ni], 0, 0, 0);
    }
    __syncthreads();

    #pragma unroll
    for (int ni = 0; ni < 2; ++ni) {
        const int col = col0 + ni * 16 + lr;
        const float bb = b2[col];
        #pragma unroll
        for (int mi = 0; mi < 2; ++mi)
            #pragma unroll
            for (int r = 0; r < 4; ++r) {
                const int e = mi * 16 + lg * 4 + r;
                *(float*)(smem + e * 1024 + col * 4) = acc[mi][ni][r] + bb;
            }
    }
    __syncthreads();

    {
        const int o0 = l * 4;
        f32x4 g2v = *(const f32x4*)(g2 + o0);
        f32x4 e2v = *(const f32x4*)(be2 + o0);
        f32x4 w3v = *(const f32x4*)(w3 + o0);
        float b3s = b3[0];
        #pragma unroll
        for (int el = 0; el < 4; ++el) {
            const int e = w * 4 + el;
            f32x4 h = *(const f32x4*)(smem + e * 1024 + o0 * 4);
            float s  = h[0] + h[1] + h[2] + h[3];
            float sq = h[0]*h[0] + h[1]*h[1] + h[2]*h[2] + h[3]*h[3];
            s = wred_add(s); sq = wred_add(sq);
            float mean = s * (1.0f / 256.0f);
            float rstd = rsqrtf(sq * (1.0f / 256.0f) - mean * mean + 1e-5f);
            float part = 0.0f;
            #pragma unroll
            for (int c = 0; c < 4; ++c) {
                float xx = (h[c] - mean) * rstd * g2v[c] + e2v[c];
                part += gelu_f(xx) * w3v[c];
            }
            part = wred_add(part);
            if (l == 0)
                out[(size_t)b * E_ + eb * 32 + e] = 1.0f / (1.0f + __expf(-(part + b3s)));
        }
    }
}

// ---------------------------------------------------------------- launch
extern "C" void kernel_launch(void* const* d_in, const int* in_sizes, int n_in,
                              void* d_out, int out_size, void* d_ws, size_t ws_size,
                              hipStream_t stream) {
    const float* verts = (const float*)d_in[0];
    const float* wp    = (const float*)d_in[1];
    const float* bp    = (const float*)d_in[2];
    const float* in_w  = (const float*)d_in[3];
    const float* in_b  = (const float*)d_in[4];
    const float* out_w = (const float*)d_in[5];
    const float* out_b = (const float*)d_in[6];
    const float* w1    = (const float*)d_in[7];
    const float* b1    = (const float*)d_in[8];
    const float* g1    = (const float*)d_in[9];
    const float* be1   = (const float*)d_in[10];
    const float* w2    = (const float*)d_in[11];
    const float* b2    = (const float*)d_in[12];
    const float* g2    = (const float*)d_in[13];
    const float* be2   = (const float*)d_in[14];
    const float* w3    = (const float*)d_in[15];
    const float* b3    = (const float*)d_in[16];
    float* out = (float*)d_out;

    const size_t MB = 1 << 20;
    char* W = (char*)d_ws;
    FrontParams fp;
    fp.verts = verts; fp.wp = wp; fp.bp = bp;
    fp.x     = (float*)(W + 0);
    fp.xfh   = (_Float16*)(W + 2*MB);
    fp.xfl   = (_Float16*)(W + 3*MB);
    fp.QKp   = (unsigned*)(W + 4*MB);            // 4MB (dead after attn)
    fp.Vp    = (unsigned*)(W + 8*MB);            // 2MB
    fp.Amat  = (float*)(W + 4*MB);               // reuse QKp
    fp.Bmat  = (float*)(W + 6*MB);
    fp.Ahf   = (_Float16*)(W + 8*MB);            // reuse Vp
    fp.Bhf   = (_Float16*)(W + 9*MB);
    fp.ctxp  = (unsigned*)(W + 10*MB);
    fp.w2    = w2;
    fp.w2f   = (_Float16*)(W + 12*MB);
    fp.etab  = (int2*)(W + 12*MB + 256*1024);
    fp.statsA= (float2*)(W + 12*MB + 512*1024);
    fp.statsB= (float2*)(W + 12*MB + 520*1024);
    fp.in_w  = in_w;
    fp.iwfh  = (_Float16*)(W + 13*MB);
    fp.iwfl  = (_Float16*)(W + 13*MB + 1536*1024);
    fp.out_w = out_w;
    fp.owfh  = (_Float16*)(W + 16*MB);
    fp.owfl  = (_Float16*)(W + 16*MB + 512*1024);
    fp.w1    = w1;
    fp.w1fh  = (_Float16*)(W + 17*MB);
    fp.w1fl  = (_Float16*)(W + 18*MB);
    fp.P     = (float*)(W + 19*MB);
    fp.in_b  = in_b; fp.out_b = out_b; fp.b1 = b1;

    void* args[] = { &fp };
    hipError_t err = hipLaunchCooperativeKernel((void*)k_front, dim3(768), dim3(256),
                                                args, 0, stream);
    if (err != hipSuccess) {
        // deterministic fallback: same math as k_front, six stage launches
        k_s0 <<<dim3(8832), dim3(256), 0, stream>>>(fp);
        k_s2 <<<dim3(768),  dim3(256), 0, stream>>>(fp);
        k_s4 <<<dim3(128),  dim3(256), 0, stream>>>(fp);
        k_s6 <<<dim3(256),  dim3(256), 0, stream>>>(fp);
        k_s8 <<<dim3(512),  dim3(256), 0, stream>>>(fp);
        k_s10<<<dim3(384),  dim3(256), 0, stream>>>(fp);
    }

    k_edge<<<dim3(B_ * 1020), dim3(512), 32768, stream>>>(fp.Amat, fp.Bmat, fp.w2f,
                                                          g1, be1, b2, g2, be2, w3, b3,
                                                          fp.etab, fp.statsA, fp.statsB, fp.P, out);
}